// Round 9
// baseline (522.968 us; speedup 1.0000x reference)
//
#include <hip/hip_runtime.h>
#include <hip/hip_bf16.h>
#include <hip/hip_cooperative_groups.h>

namespace cg = cooperative_groups;

// Problem constants
constexpr int Bc = 2, Sc = 2048, Ec = 1024, Hc = 16, Dc = 64;
constexpr int Mrows = Bc * Sc;   // 4096
constexpr int Kdim  = Ec;        // 1024

// 0.125 (score scale) * log2(e), folded into q at projection time
#define QSCALE 0.18033688011112042f

typedef float  floatx4 __attribute__((ext_vector_type(4)));
typedef short  shortx8 __attribute__((ext_vector_type(8)));

__device__ __forceinline__ unsigned int pack2bf(float a, float b) {
    union { float f; unsigned int u; } ca, cb;
    ca.f = a; cb.f = b;
    return ((ca.u + 0x8000u) >> 16) | ((cb.u + 0x8000u) & 0xffff0000u);
}
__device__ inline float exp2_fast(float x) {
#if __has_builtin(__builtin_amdgcn_exp2f)
    return __builtin_amdgcn_exp2f(x);
#else
    return __expf(x * 0.69314718056f);
#endif
}

// async global->LDS DMA, 16 B/lane; HW dest = wave-uniform base + lane*16.
__device__ __forceinline__ void gll16(const void* g, void* lds) {
    __builtin_amdgcn_global_load_lds(
        (const __attribute__((address_space(1))) void*)g,
        (__attribute__((address_space(3))) void*)lds, 16, 0, 0);
}

// ===========================================================================
// Phase device functions (shared by the cooperative kernel and the fallback
// per-phase kernels). All sized for GRID = 512 blocks x 256 threads.
// ===========================================================================

// ---- phase 0: convert fp32 -> bf16 (grid-stride over 512*256 threads) -----
__device__ __forceinline__ void phase_convert(
    int bx, int tid,
    const float* __restrict__ x,  const float* __restrict__ Wq,
    const float* __restrict__ Wk, const float* __restrict__ Wv,
    const float* __restrict__ Wc,
    unsigned short* __restrict__ xb,  unsigned short* __restrict__ Wqb,
    unsigned short* __restrict__ Wkb, unsigned short* __restrict__ Wvb,
    unsigned short* __restrict__ Wcb)
{
    const long gtid = (long)bx * 256 + tid;
    for (long t = gtid; t < 2097152; t += 131072) {
        const long i = t * 4;
        const float* src; unsigned short* dst; long off;
        if (i < 4194304) { src = x; dst = xb; off = i; }
        else {
            long j = i - 4194304;
            int wsel = (int)(j >> 20);
            off = j & 1048575;
            src = (wsel == 0) ? Wq : (wsel == 1) ? Wk : (wsel == 2) ? Wv : Wc;
            dst = (wsel == 0) ? Wqb : (wsel == 1) ? Wkb : (wsel == 2) ? Wvb : Wcb;
        }
        float4 v = *(const float4*)(src + off);
        uint2 u;
        u.x = pack2bf(v.x, v.y);
        u.y = pack2bf(v.z, v.w);
        *(uint2*)(dst + off) = u;
    }
}

// ---- phase 1: projections, 64x128 tiles, 1536 tiles = 512 blocks x 3 ------
__device__ __forceinline__ void phase_proj(
    char* smem, int bx, int tid,
    const unsigned short* __restrict__ xb,
    const unsigned short* __restrict__ Wqb,
    const unsigned short* __restrict__ Wkb,
    const unsigned short* __restrict__ Wvb,
    unsigned short* __restrict__ qg, unsigned short* __restrict__ kg,
    unsigned short* __restrict__ vtg)
{
    const int lane = tid & 63;
    const int w = tid >> 6, l15 = tid & 15, quad = (tid >> 4) & 3;
    const int wq = w >> 1, wn = w & 1;
    const int sw = l15 & 7;
    float (*Cs)[132] = (float(*)[132])smem;          // 64*132*4 = 33792 B
    float (*Sp)[9]   = (float(*)[9])(smem + 33792);  // 2304 B

    for (int t = bx; t < 1536; t += 512) {
        const int z   = t >> 9;            // 0,1,2 across the 3 passes
        const int rem = t & 511;
        const int m0  = (rem & 63) * 64;
        const int n0  = (rem >> 6) * 128;
        const unsigned short* Wb = (z == 0) ? Wqb : (z == 1) ? Wkb : Wvb;
        unsigned short* po       = (z == 0) ? qg  : (z == 1) ? kg  : vtg;
        const float osc = (z == 0) ? QSCALE : 1.0f;

        floatx4 acc[2][4];
        #pragma unroll
        for (int ms = 0; ms < 2; ++ms)
            #pragma unroll
            for (int ns = 0; ns < 4; ++ns)
                #pragma unroll
                for (int e = 0; e < 4; ++e) acc[ms][ns][e] = 0.0f;

        for (int k0 = 0; k0 < Kdim; k0 += 64) {
            #pragma unroll
            for (int j = 0; j < 2; ++j) {
                int idx = j * 64 + lane;
                int row = 16 * w + (idx >> 3);
                int cg2 = ((idx & 7) ^ (idx >> 3)) & 7;
                gll16(xb + (size_t)(m0 + row) * Kdim + k0 + cg2 * 8,
                      smem + 2048 * w + 1024 * j);
            }
            #pragma unroll
            for (int j = 0; j < 4; ++j) {
                int idx = j * 64 + lane;
                int row = 32 * w + (idx >> 3);
                int cg2 = ((idx & 7) ^ (idx >> 3)) & 7;
                gll16(Wb + (size_t)(n0 + row) * Kdim + k0 + cg2 * 8,
                      smem + 8192 + 4096 * w + 1024 * j);
            }
            __syncthreads();
            #pragma unroll
            for (int ks = 0; ks < 2; ++ks) {
                shortx8 af[2], bf[4];
                #pragma unroll
                for (int ms = 0; ms < 2; ++ms)
                    af[ms] = *(shortx8*)(smem + (32 * wq + 16 * ms + l15) * 128
                                         + (((4 * ks + quad) ^ sw) << 4));
                #pragma unroll
                for (int ns = 0; ns < 4; ++ns)
                    bf[ns] = *(shortx8*)(smem + 8192 + (64 * wn + 16 * ns + l15) * 128
                                         + (((4 * ks + quad) ^ sw) << 4));
                #pragma unroll
                for (int ms = 0; ms < 2; ++ms)
                    #pragma unroll
                    for (int ns = 0; ns < 4; ++ns)
                        acc[ms][ns] = __builtin_amdgcn_mfma_f32_16x16x32_bf16(
                            af[ms], bf[ns], acc[ms][ns], 0, 0, 0);
            }
            __syncthreads();
        }

        // epilogue: cos -> per-head cumprod -> write (single 64-row pass)
        #pragma unroll
        for (int ms = 0; ms < 2; ++ms)
            #pragma unroll
            for (int ns = 0; ns < 4; ++ns)
                #pragma unroll
                for (int r = 0; r < 4; ++r)
                    Cs[32 * wq + 16 * ms + 4 * quad + r][64 * wn + 16 * ns + l15] =
                        __cosf(acc[ms][ns][r]);
        __syncthreads();
        #pragma unroll
        for (int t2 = tid; t2 < 512; t2 += 256) {
            int row = t2 >> 3, seg = t2 & 7;
            float pr = 1.0f;
            #pragma unroll
            for (int c = 0; c < 16; ++c) pr *= Cs[row][seg * 16 + c];
            Sp[row][seg] = pr;
        }
        __syncthreads();

        const int b = m0 >> 11;
        const int sbase = m0 & (Sc - 1);
        const int h0 = n0 >> 6;

        if (z != 2) {
            #pragma unroll
            for (int t2 = tid; t2 < 512; t2 += 256) {
                int row = t2 >> 3, seg = t2 & 7;
                float p = 1.0f;
                for (int j = (seg & 4); j < seg; ++j) p *= Sp[row][j];
                unsigned int dw[8];
                #pragma unroll
                for (int c2 = 0; c2 < 8; ++c2) {
                    p *= Cs[row][seg * 16 + 2 * c2];     float a = p * osc;
                    p *= Cs[row][seg * 16 + 2 * c2 + 1]; float bb = p * osc;
                    dw[c2] = pack2bf(a, bb);
                }
                int h = h0 + (seg >> 2);
                int s = sbase + row;
                size_t base = (((size_t)b * Hc + h) * Sc + s) * Dc + (seg & 3) * 16;
                *(uint4*)(po + base)     = *(uint4*)&dw[0];
                *(uint4*)(po + base + 8) = *(uint4*)&dw[4];
            }
            __syncthreads();
        } else {
            #pragma unroll
            for (int t2 = tid; t2 < 512; t2 += 256) {
                int row = t2 >> 3, seg = t2 & 7;
                float p = 1.0f;
                for (int j = (seg & 4); j < seg; ++j) p *= Sp[row][j];
                #pragma unroll
                for (int c = 0; c < 16; ++c) { p *= Cs[row][seg * 16 + c]; Cs[row][seg * 16 + c] = p; }
            }
            __syncthreads();
            #pragma unroll
            for (int t2 = tid; t2 < 512; t2 += 256) {
                int col = t2 >> 2, chunk = t2 & 3;   // col 0..127, chunk 0..3
                int h = h0 + (col >> 6), d = col & 63;
                unsigned int dw[8];
                #pragma unroll
                for (int j2 = 0; j2 < 8; ++j2)
                    dw[j2] = pack2bf(Cs[chunk * 16 + 2 * j2][col],
                                     Cs[chunk * 16 + 2 * j2 + 1][col]);
                size_t base = (((size_t)b * Hc + h) * Dc + d) * Sc
                              + sbase + chunk * 16;
                *(uint4*)(po + base)     = *(uint4*)&dw[0];
                *(uint4*)(po + base + 8) = *(uint4*)&dw[4];
            }
            __syncthreads();
        }
    }
}

// ---- phase 2: flash attention, full S, 512 blocks (16 qb x 32 bh) ---------
__device__ __forceinline__ void phase_attn(
    char* smem, int bx, int tid,
    const unsigned short* __restrict__ qg, const unsigned short* __restrict__ kg,
    const unsigned short* __restrict__ vtg, unsigned short* __restrict__ attb)
{
    const int lane = tid & 63;
    const int w = tid >> 6, l15 = tid & 15, quad = (tid >> 4) & 3;
    const int sw = l15 & 7;
    const int qb = bx & 15;
    const int bh = bx >> 4;

    const unsigned short* qp = qg  + (size_t)bh * Sc * Dc;
    const unsigned short* kp = kg  + (size_t)bh * Sc * Dc;
    const unsigned short* vp = vtg + (size_t)bh * Dc * Sc;

    unsigned short (*Pq)[72] = (unsigned short(*)[72])(smem + 16384);

    int qrow[2];
    shortx8 qf[2][2];
    #pragma unroll
    for (int qs = 0; qs < 2; ++qs) {
        qrow[qs] = qb * 128 + 32 * w + 16 * qs + l15;
        qf[qs][0] = *(const shortx8*)(qp + (size_t)qrow[qs] * Dc + 8 * quad);
        qf[qs][1] = *(const shortx8*)(qp + (size_t)qrow[qs] * Dc + 32 + 8 * quad);
    }

    floatx4 Oacc[2][4];
    #pragma unroll
    for (int qs = 0; qs < 2; ++qs)
        #pragma unroll
        for (int mt = 0; mt < 4; ++mt)
            #pragma unroll
            for (int e = 0; e < 4; ++e) Oacc[qs][mt][e] = 0.0f;
    float lsum[2] = {0.0f, 0.0f};

    for (int kt = 0; kt < 32; ++kt) {
        #pragma unroll
        for (int j = 0; j < 2; ++j) {
            int idx = j * 64 + lane;
            int row = 16 * w + (idx >> 3);
            int cg2 = ((idx & 7) ^ (idx >> 3)) & 7;
            gll16(kp + (size_t)(kt * 64 + row) * Dc + cg2 * 8,
                  smem + 2048 * w + 1024 * j);
            gll16(vp + (size_t)row * Sc + kt * 64 + cg2 * 8,
                  smem + 8192 + 2048 * w + 1024 * j);
        }
        __syncthreads();

        shortx8 kf[2][4], vf[2][4];
        #pragma unroll
        for (int ks = 0; ks < 2; ++ks)
            #pragma unroll
            for (int mt = 0; mt < 4; ++mt) {
                int off = (16 * mt + l15) * 128 + (((4 * ks + quad) ^ sw) << 4);
                kf[ks][mt] = *(shortx8*)(smem + off);
                vf[ks][mt] = *(shortx8*)(smem + 8192 + off);
            }

        #pragma unroll
        for (int qs = 0; qs < 2; ++qs) {
            floatx4 st[4];
            #pragma unroll
            for (int mt = 0; mt < 4; ++mt)
                #pragma unroll
                for (int e = 0; e < 4; ++e) st[mt][e] = 0.0f;
            #pragma unroll
            for (int ks = 0; ks < 2; ++ks)
                #pragma unroll
                for (int mt = 0; mt < 4; ++mt)
                    st[mt] = __builtin_amdgcn_mfma_f32_16x16x32_bf16(
                        kf[ks][mt], qf[qs][ks], st[mt], 0, 0, 0);

            float rs = 0.0f;
            #pragma unroll
            for (int mt = 0; mt < 4; ++mt) {
                float p0 = exp2_fast(st[mt][0]);
                float p1 = exp2_fast(st[mt][1]);
                float p2 = exp2_fast(st[mt][2]);
                float p3 = exp2_fast(st[mt][3]);
                rs += (p0 + p1) + (p2 + p3);
                uint2 u;
                u.x = pack2bf(p0, p1);
                u.y = pack2bf(p2, p3);
                *(uint2*)&Pq[32 * w + 16 * qs + l15][16 * mt + 4 * quad] = u;
            }
            lsum[qs] += rs;

            #pragma unroll
            for (int ks = 0; ks < 2; ++ks) {
                shortx8 pf = *(shortx8*)&Pq[32 * w + 16 * qs + l15][32 * ks + 8 * quad];
                #pragma unroll
                for (int mt = 0; mt < 4; ++mt)
                    Oacc[qs][mt] = __builtin_amdgcn_mfma_f32_16x16x32_bf16(
                        vf[ks][mt], pf, Oacc[qs][mt], 0, 0, 0);
            }
        }
        __syncthreads();
    }

    const int b = bh >> 4, hh = bh & 15;
    #pragma unroll
    for (int qs = 0; qs < 2; ++qs) {
        float l = lsum[qs];
        l += __shfl_xor(l, 16, 64);
        l += __shfl_xor(l, 32, 64);
        const float inv = 1.0f / l;
        #pragma unroll
        for (int mt = 0; mt < 4; ++mt) {
            uint2 u;
            u.x = pack2bf(Oacc[qs][mt][0] * inv, Oacc[qs][mt][1] * inv);
            u.y = pack2bf(Oacc[qs][mt][2] * inv, Oacc[qs][mt][3] * inv);
            size_t base = ((size_t)b * Sc + qrow[qs]) * Ec + hh * 64 + 16 * mt + 4 * quad;
            *(uint2*)(attb + base) = u;
        }
    }
}

// ---- phase 3: out-projection, 64x128 tiles, 512 blocks --------------------
__device__ __forceinline__ void phase_outproj(
    char* smem, int bx, int tid,
    const unsigned short* __restrict__ attb,
    const unsigned short* __restrict__ Wcb,
    const float* __restrict__ bias, float* __restrict__ out)
{
    const int lane = tid & 63;
    const int w = tid >> 6, l15 = tid & 15, quad = (tid >> 4) & 3;
    const int wq = w >> 1, wn = w & 1;
    const int sw = l15 & 7;
    const int m0 = (bx & 63) * 64;
    const int n0 = (bx >> 6) * 128;

    floatx4 acc[2][4];
    #pragma unroll
    for (int ms = 0; ms < 2; ++ms)
        #pragma unroll
        for (int ns = 0; ns < 4; ++ns)
            #pragma unroll
            for (int e = 0; e < 4; ++e) acc[ms][ns][e] = 0.0f;

    for (int k0 = 0; k0 < Kdim; k0 += 64) {
        #pragma unroll
        for (int j = 0; j < 2; ++j) {
            int idx = j * 64 + lane;
            int row = 16 * w + (idx >> 3);
            int cg2 = ((idx & 7) ^ (idx >> 3)) & 7;
            gll16(attb + (size_t)(m0 + row) * Kdim + k0 + cg2 * 8,
                  smem + 2048 * w + 1024 * j);
        }
        #pragma unroll
        for (int j = 0; j < 4; ++j) {
            int idx = j * 64 + lane;
            int row = 32 * w + (idx >> 3);
            int cg2 = ((idx & 7) ^ (idx >> 3)) & 7;
            gll16(Wcb + (size_t)(n0 + row) * Kdim + k0 + cg2 * 8,
                  smem + 8192 + 4096 * w + 1024 * j);
        }
        __syncthreads();
        #pragma unroll
        for (int ks = 0; ks < 2; ++ks) {
            shortx8 af[2], bf[4];
            #pragma unroll
            for (int ms = 0; ms < 2; ++ms)
                af[ms] = *(shortx8*)(smem + (32 * wq + 16 * ms + l15) * 128
                                     + (((4 * ks + quad) ^ sw) << 4));
            #pragma unroll
            for (int ns = 0; ns < 4; ++ns)
                bf[ns] = *(shortx8*)(smem + 8192 + (64 * wn + 16 * ns + l15) * 128
                                     + (((4 * ks + quad) ^ sw) << 4));
            #pragma unroll
            for (int ms = 0; ms < 2; ++ms)
                #pragma unroll
                for (int ns = 0; ns < 4; ++ns)
                    acc[ms][ns] = __builtin_amdgcn_mfma_f32_16x16x32_bf16(
                        af[ms], bf[ns], acc[ms][ns], 0, 0, 0);
        }
        __syncthreads();
    }

    #pragma unroll
    for (int ns = 0; ns < 4; ++ns) {
        const float bv = bias[n0 + 64 * wn + 16 * ns + l15];
        #pragma unroll
        for (int ms = 0; ms < 2; ++ms)
            #pragma unroll
            for (int r = 0; r < 4; ++r) {
                int m = m0 + 32 * wq + 16 * ms + 4 * quad + r;
                out[(size_t)m * Kdim + n0 + 64 * wn + 16 * ns + l15] =
                    acc[ms][ns][r] + bv;
            }
    }
}

// ===========================================================================
// Cooperative fused kernel: 512 blocks x 256 threads (2 blocks/CU).
// ===========================================================================
__global__ __launch_bounds__(256, 2) void fused_kernel(
    const float* __restrict__ x,  const float* __restrict__ Wq,
    const float* __restrict__ Wk, const float* __restrict__ Wv,
    const float* __restrict__ Wc, const float* __restrict__ bc,
    unsigned short* __restrict__ xb,  unsigned short* __restrict__ Wqb,
    unsigned short* __restrict__ Wkb, unsigned short* __restrict__ Wvb,
    unsigned short* __restrict__ Wcb,
    unsigned short* __restrict__ qg, unsigned short* __restrict__ kg,
    unsigned short* __restrict__ vtg, unsigned short* __restrict__ attb,
    float* __restrict__ out)
{
    cg::grid_group grid = cg::this_grid();
    __shared__ __align__(16) char smem[36096];
    const int bx = blockIdx.x, tid = threadIdx.x;

    phase_convert(bx, tid, x, Wq, Wk, Wv, Wc, xb, Wqb, Wkb, Wvb, Wcb);
    __threadfence();
    grid.sync();
    phase_proj(smem, bx, tid, xb, Wqb, Wkb, Wvb, qg, kg, vtg);
    __threadfence();
    grid.sync();
    phase_attn(smem, bx, tid, qg, kg, vtg, attb);
    __threadfence();
    grid.sync();
    phase_outproj(smem, bx, tid, attb, Wcb, bc, out);
}

// ===========================================================================
// Fallback per-phase kernels (identical math; used if cooperative launch
// is rejected by the runtime).
// ===========================================================================
__global__ __launch_bounds__(256) void k_convert(
    const float* x, const float* Wq, const float* Wk, const float* Wv,
    const float* Wc, unsigned short* xb, unsigned short* Wqb,
    unsigned short* Wkb, unsigned short* Wvb, unsigned short* Wcb)
{
    phase_convert(blockIdx.x, threadIdx.x, x, Wq, Wk, Wv, Wc, xb, Wqb, Wkb, Wvb, Wcb);
}
__global__ __launch_bounds__(256) void k_proj(
    const unsigned short* xb, const unsigned short* Wqb,
    const unsigned short* Wkb, const unsigned short* Wvb,
    unsigned short* qg, unsigned short* kg, unsigned short* vtg)
{
    __shared__ __align__(16) char smem[36096];
    phase_proj(smem, blockIdx.x, threadIdx.x, xb, Wqb, Wkb, Wvb, qg, kg, vtg);
}
__global__ __launch_bounds__(256) void k_attn(
    const unsigned short* qg, const unsigned short* kg,
    const unsigned short* vtg, unsigned short* attb)
{
    __shared__ __align__(16) char smem[36096];
    phase_attn(smem, blockIdx.x, threadIdx.x, qg, kg, vtg, attb);
}
__global__ __launch_bounds__(256) void k_outproj(
    const unsigned short* attb, const unsigned short* Wcb,
    const float* bias, float* out)
{
    __shared__ __align__(16) char smem[36096];
    phase_outproj(smem, blockIdx.x, threadIdx.x, attb, Wcb, bias, out);
}

// ---------------------------------------------------------------------------
extern "C" void kernel_launch(void* const* d_in, const int* in_sizes, int n_in,
                              void* d_out, int out_size, void* d_ws, size_t ws_size,
                              hipStream_t stream) {
    const float* x  = (const float*)d_in[0];
    const float* Wq = (const float*)d_in[1];
    const float* Wk = (const float*)d_in[2];
    const float* Wv = (const float*)d_in[3];
    const float* Wc = (const float*)d_in[4];
    const float* bc = (const float*)d_in[5];
    float* out = (float*)d_out;

    // ws layout (48 MB): xb 8M | Wqb/Wkb/Wvb/Wcb 2M ea | qb 8M | kb 8M | vtb 8M | attb 8M
    char* p = (char*)d_ws;
    unsigned short* xb   = (unsigned short*)(p);
    unsigned short* Wqb  = (unsigned short*)(p + (8u << 20));
    unsigned short* Wkb  = (unsigned short*)(p + (10u << 20));
    unsigned short* Wvb  = (unsigned short*)(p + (12u << 20));
    unsigned short* Wcb  = (unsigned short*)(p + (14u << 20));
    unsigned short* qb_  = (unsigned short*)(p + (16u << 20));
    unsigned short* kb_  = (unsigned short*)(p + (24u << 20));
    unsigned short* vtb  = (unsigned short*)(p + (32u << 20));
    unsigned short* attb = (unsigned short*)(p + (40u << 20));

    void* args[] = {
        (void*)&x, (void*)&Wq, (void*)&Wk, (void*)&Wv, (void*)&Wc, (void*)&bc,
        (void*)&xb, (void*)&Wqb, (void*)&Wkb, (void*)&Wvb, (void*)&Wcb,
        (void*)&qb_, (void*)&kb_, (void*)&vtb, (void*)&attb, (void*)&out
    };
    hipError_t err = hipLaunchCooperativeKernel((const void*)fused_kernel,
                                                dim3(512), dim3(256),
                                                args, 0, stream);
    if (err != hipSuccess) {
        // Fallback: same phases as ordinary dependent launches.
        hipLaunchKernelGGL(k_convert, dim3(512), dim3(256), 0, stream,
                           x, Wq, Wk, Wv, Wc, xb, Wqb, Wkb, Wvb, Wcb);
        hipLaunchKernelGGL(k_proj, dim3(512), dim3(256), 0, stream,
                           xb, Wqb, Wkb, Wvb, qb_, kb_, vtb);
        hipLaunchKernelGGL(k_attn, dim3(512), dim3(256), 0, stream,
                           qb_, kb_, vtb, attb);
        hipLaunchKernelGGL(k_outproj, dim3(512), dim3(256), 0, stream,
                           attb, Wcb, bc, out);
    }
}